// Round 6
// baseline (206.460 us; speedup 1.0000x reference)
//
#include <hip/hip_runtime.h>
#include <hip/hip_bf16.h>

// B=4, S=2048, D=512. fp32 in/out, bf16 MFMA internals.
//   cvt: q,k,v,W* fp32 -> bf16
//   proj3: qp = q@WQ^T+b, kp = k@WK^T+b, vpT = (v@WV^T+b)^T  (one launch, z=0..2)
//   scores: E = exp(mask(scale*qp@kp^T)) bf16, masked(q<k)=1; fused Z[k]=sum_q E[q][k]
//   scale:  vpT[b][d][k] /= Z[b][k]
//   out:    E @ vpT^T -> fp32 d_out (64x128 tiles, full K, no split)
// GEMM core: 128x128 tile, BK=32, global_load_lds width-16 staging, XOR-swizzled
// column groups (ds_read_b128 2-way/free). bf16 epilogues go through an LDS
// transpose (stride-68 pad) so global stores are 16B-coalesced s8v.

#define S_LEN 2048
#define D_DIM 512
#define SCALE_F 0.044194173824159216f  // 1/sqrt(512)

typedef __attribute__((ext_vector_type(8))) short s8v;   // 8 bf16 = 4 VGPRs
typedef __attribute__((ext_vector_type(4))) short s4v;   // 4 bf16 = 8 B
typedef __attribute__((ext_vector_type(4))) float f4v;   // MFMA accumulator

enum { EPI_BIAS = 0, EPI_BIAS_T = 1, EPI_SCORES = 2 };

__device__ __forceinline__ short f2bf_s(float f) {
  union { __hip_bfloat16 b; short s; } u; u.b = __float2bfloat16(f); return u.s;
}
__device__ __forceinline__ float bf2f_s(short h) {
  union { short s; __hip_bfloat16 b; } u; u.s = h; return __bfloat162float(u.b);
}

__device__ __forceinline__ void glds16(const short* g, short* l) {
  __builtin_amdgcn_global_load_lds((const __attribute__((address_space(1))) void*)g,
                                   (__attribute__((address_space(3))) void*)l, 16, 0, 0);
}

// Core NT GEMM, 128x128 tile at (m0,n0). A,B offset to batch. SMEM: 8704 shorts.
// Staging uses SMEM[0..8191] (As/Bs 128x32 each); bf16 epilogue reuses SMEM as
// per-wave 32x64 transpose buffers (stride 68, 2176 shorts/wave).
template <int EPI>
__device__ __forceinline__ void gemm_core(
    const short* __restrict__ A, const short* __restrict__ B,
    short* __restrict__ C, const float* __restrict__ bias,
    short* SMEM, int N, int K, size_t sCz, int m0, int n0, int bz,
    float* __restrict__ Z)
{
  short* As = SMEM;
  short* Bs = SMEM + 4096;

  const int tid  = threadIdx.x;
  const int w    = tid >> 6;
  const int lane = tid & 63;
  const int quad = lane >> 4;
  const int l16  = lane & 15;
  const int wm   = (w >> 1) * 64;
  const int wn   = (w & 1) * 64;

  const int sr = tid >> 2;                                            // 0..63
  const int g8 = (((tid & 3) ^ ((tid >> 2) & 3) ^ ((tid >> 4) & 3))) * 8;

  f4v acc[4][4];
#pragma unroll
  for (int i = 0; i < 4; ++i)
#pragma unroll
    for (int j = 0; j < 4; ++j)
#pragma unroll
      for (int r = 0; r < 4; ++r) acc[i][j][r] = 0.0f;

  const short* Ag = A + (size_t)(m0 + sr) * K + g8;
  const short* Bg = B + (size_t)(n0 + sr) * K + g8;
  short* Asl = As + tid * 8;
  short* Bsl = Bs + tid * 8;
  const size_t rowskip = (size_t)64 * K;

  const int sw = ((l16 & 3) ^ ((l16 >> 2) & 3)) * 8;   // read-side swizzle

  for (int k0 = 0; k0 < K; k0 += 32) {
    glds16(Ag + k0,           Asl);
    glds16(Ag + k0 + rowskip, Asl + 2048);
    glds16(Bg + k0,           Bsl);
    glds16(Bg + k0 + rowskip, Bsl + 2048);
    __syncthreads();

    s8v af[4], bf[4];
#pragma unroll
    for (int i = 0; i < 4; ++i)
      af[i] = *(const s8v*)&As[(wm + i * 16 + l16) * 32 + ((quad * 8) ^ sw)];
#pragma unroll
    for (int j = 0; j < 4; ++j)
      bf[j] = *(const s8v*)&Bs[(wn + j * 16 + l16) * 32 + ((quad * 8) ^ sw)];

#pragma unroll
    for (int i = 0; i < 4; ++i)
#pragma unroll
      for (int j = 0; j < 4; ++j)
        acc[i][j] = __builtin_amdgcn_mfma_f32_16x16x32_bf16(af[i], bf[j], acc[i][j], 0, 0, 0);

    __syncthreads();
  }

  // ---- epilogue ----
  float bv[4];
  if (EPI == EPI_BIAS || EPI == EPI_BIAS_T) {
#pragma unroll
    for (int j = 0; j < 4; ++j) bv[j] = bias[n0 + wn + j * 16 + l16];
  }

  if (EPI == EPI_BIAS_T) {
    // vpT[b][gn][ss]: 4 consecutive ss per lane -> one 8B store
#pragma unroll
    for (int i = 0; i < 4; ++i) {
#pragma unroll
      for (int j = 0; j < 4; ++j) {
        const int gn  = n0 + wn + j * 16 + l16;
        const int gmb = m0 + wm + i * 16 + quad * 4;
        const int bb = gmb >> 11, ssb = gmb & (S_LEN - 1);
        s4v o;
#pragma unroll
        for (int r = 0; r < 4; ++r) o[r] = f2bf_s(acc[i][j][r] + bv[j]);
        *(s4v*)&C[((size_t)bb * D_DIM + gn) * S_LEN + ssb] = o;
      }
    }
    return;
  }

  // EPI_BIAS / EPI_SCORES: LDS transpose -> coalesced 16B row stores.
  short* TB = SMEM;                 // 4 waves x 2176 shorts (32 rows x stride 68)
  const int wbase = w * 2176;
  float csum[4] = {0.f, 0.f, 0.f, 0.f};

#pragma unroll
  for (int ph = 0; ph < 2; ++ph) {
    __syncthreads();
#pragma unroll
    for (int ii = 0; ii < 2; ++ii) {
      const int i = ph * 2 + ii;
#pragma unroll
      for (int j = 0; j < 4; ++j) {
        const int gn = n0 + wn + j * 16 + l16;
#pragma unroll
        for (int r = 0; r < 4; ++r) {
          short o;
          if (EPI == EPI_SCORES) {
            const int gm = m0 + wm + i * 16 + quad * 4 + r;
            const float e = (gm >= gn) ? __expf(acc[i][j][r] * SCALE_F) : 1.0f;
            csum[j] += e;
            o = f2bf_s(e);
          } else {
            o = f2bf_s(acc[i][j][r] + bv[j]);
          }
          TB[wbase + (ii * 16 + quad * 4 + r) * 68 + j * 16 + l16] = o;
        }
      }
    }
    __syncthreads();
#pragma unroll
    for (int p = 0; p < 4; ++p) {
      const int row = p * 8 + (lane >> 3);   // 0..31
      const int cg  = lane & 7;
      const s8v vv = *(const s8v*)&TB[wbase + row * 68 + cg * 8];
      const int gm = m0 + wm + ph * 32 + row;
      const int gn = n0 + wn + cg * 8;
      *(s8v*)&C[sCz + (size_t)gm * N + gn] = vv;
    }
  }

  if (EPI == EPI_SCORES) {
#pragma unroll
    for (int j = 0; j < 4; ++j) {
      float cs = csum[j];
      cs += __shfl_xor(cs, 16, 64);
      cs += __shfl_xor(cs, 32, 64);
      if (quad == 0) atomicAdd(&Z[(bz << 11) + n0 + wn + j * 16 + l16], cs);
    }
  }
}

// scores kernel
__global__ __launch_bounds__(256, 2) void gemm_scores(
    const short* __restrict__ A, const short* __restrict__ B, short* __restrict__ C,
    float* __restrict__ Z)
{
  __shared__ __align__(16) short SMEM[8704];
  const int bz = blockIdx.z;
  gemm_core<EPI_SCORES>(A + (size_t)bz * S_LEN * D_DIM, B + (size_t)bz * S_LEN * D_DIM,
                        C, nullptr, SMEM, S_LEN, D_DIM,
                        (size_t)bz * S_LEN * S_LEN, blockIdx.y * 128, blockIdx.x * 128,
                        bz, Z);
}

// three projections in one launch: z=0 -> qp, z=1 -> kp, z=2 -> vpT (transposed)
__global__ __launch_bounds__(256, 2) void proj3(
    const short* __restrict__ a0, const short* __restrict__ a1, const short* __restrict__ a2,
    const short* __restrict__ b0, const short* __restrict__ b1, const short* __restrict__ b2,
    short* __restrict__ c0, short* __restrict__ c1, short* __restrict__ c2,
    const float* __restrict__ x0, const float* __restrict__ x1, const float* __restrict__ x2)
{
  __shared__ __align__(16) short SMEM[8704];
  const int z = blockIdx.z;
  const short* A = (z == 0) ? a0 : (z == 1) ? a1 : a2;
  const short* B = (z == 0) ? b0 : (z == 1) ? b1 : b2;
  short*       C = (z == 0) ? c0 : (z == 1) ? c1 : c2;
  const float* bias = (z == 0) ? x0 : (z == 1) ? x1 : x2;
  if (z == 2)
    gemm_core<EPI_BIAS_T>(A, B, C, bias, SMEM, D_DIM, D_DIM, 0,
                          blockIdx.y * 128, blockIdx.x * 128, 0, nullptr);
  else
    gemm_core<EPI_BIAS>(A, B, C, bias, SMEM, D_DIM, D_DIM, 0,
                        blockIdx.y * 128, blockIdx.x * 128, 0, nullptr);
}

// out = E @ vpT^T, per batch M=2048 N=512 K=2048, 64x128 tiles, full K, fp32 out
__global__ __launch_bounds__(256, 2) void gemm_out(
    const short* __restrict__ E, const short* __restrict__ vpT,
    float* __restrict__ out)
{
  __shared__ __align__(16) short As[64 * 32];    // 4 KB
  __shared__ __align__(16) short Bs[128 * 32];   // 8 KB

  const int tid  = threadIdx.x;
  const int bz   = blockIdx.z;
  const int m0   = blockIdx.y * 64;
  const int n0   = blockIdx.x * 128;

  const short* A = E   + (size_t)bz * S_LEN * S_LEN;
  const short* B = vpT + (size_t)bz * D_DIM * S_LEN;

  const int w    = tid >> 6;
  const int lane = tid & 63;
  const int quad = lane >> 4;
  const int l16  = lane & 15;
  const int wm   = (w >> 1) * 32;
  const int wn   = (w & 1) * 64;

  const int sr = tid >> 2;
  const int g8 = (((tid & 3) ^ ((tid >> 2) & 3) ^ ((tid >> 4) & 3))) * 8;

  f4v acc[2][4];
#pragma unroll
  for (int i = 0; i < 2; ++i)
#pragma unroll
    for (int j = 0; j < 4; ++j)
#pragma unroll
      for (int r = 0; r < 4; ++r) acc[i][j][r] = 0.0f;

  const short* Ag = A + (size_t)(m0 + sr) * S_LEN + g8;
  const short* Bg = B + (size_t)(n0 + sr) * S_LEN + g8;
  short* Asl = As + tid * 8;
  short* Bsl = Bs + tid * 8;
  const size_t rowskip = (size_t)64 * S_LEN;

  const int sw = ((l16 & 3) ^ ((l16 >> 2) & 3)) * 8;

  for (int k0 = 0; k0 < S_LEN; k0 += 32) {
    glds16(Ag + k0,           Asl);
    glds16(Bg + k0,           Bsl);
    glds16(Bg + k0 + rowskip, Bsl + 2048);
    __syncthreads();

    s8v af[2], bf[4];
#pragma unroll
    for (int i = 0; i < 2; ++i)
      af[i] = *(const s8v*)&As[(wm + i * 16 + l16) * 32 + ((quad * 8) ^ sw)];
#pragma unroll
    for (int j = 0; j < 4; ++j)
      bf[j] = *(const s8v*)&Bs[(wn + j * 16 + l16) * 32 + ((quad * 8) ^ sw)];

#pragma unroll
    for (int i = 0; i < 2; ++i)
#pragma unroll
      for (int j = 0; j < 4; ++j)
        acc[i][j] = __builtin_amdgcn_mfma_f32_16x16x32_bf16(af[i], bf[j], acc[i][j], 0, 0, 0);

    __syncthreads();
  }

  float* Cf = out + (size_t)bz * S_LEN * D_DIM;
#pragma unroll
  for (int i = 0; i < 2; ++i) {
#pragma unroll
    for (int j = 0; j < 4; ++j) {
      const int gn = n0 + wn + j * 16 + l16;
#pragma unroll
      for (int r = 0; r < 4; ++r) {
        const int gm = m0 + wm + i * 16 + quad * 4 + r;
        Cf[(size_t)gm * D_DIM + gn] = acc[i][j][r];
      }
    }
  }
}

// fp32 -> bf16, 8 elems/thread, three source arrays -> contiguous dst slabs
__global__ __launch_bounds__(256) void cvt3(
    const float* __restrict__ s0, const float* __restrict__ s1,
    const float* __restrict__ s2, short* __restrict__ dst, int n)
{
  const float* s = (blockIdx.y == 0) ? s0 : (blockIdx.y == 1) ? s1 : s2;
  short* d = dst + (size_t)blockIdx.y * n;
  const int i = (blockIdx.x * 256 + threadIdx.x) * 8;
  if (i >= n) return;
  const float4 f0 = *(const float4*)(s + i);
  const float4 f1 = *(const float4*)(s + i + 4);
  s8v o;
  o[0] = f2bf_s(f0.x); o[1] = f2bf_s(f0.y); o[2] = f2bf_s(f0.z); o[3] = f2bf_s(f0.w);
  o[4] = f2bf_s(f1.x); o[5] = f2bf_s(f1.y); o[6] = f2bf_s(f1.z); o[7] = f2bf_s(f1.w);
  *(s8v*)(d + i) = o;
}

// vpT[b][d][k] *= 1/Z[b][k], 8 consecutive k per thread
__global__ __launch_bounds__(256) void scale_vpt(
    short* __restrict__ vpT, const float* __restrict__ Z)
{
  const size_t base = ((size_t)blockIdx.x * 256 + threadIdx.x) * 8;  // < 2^22
  const int kk = (int)(base & (S_LEN - 1));
  const int b  = (int)(base >> 20);
  const float4 z0 = *(const float4*)&Z[(b << 11) + kk];
  const float4 z1 = *(const float4*)&Z[(b << 11) + kk + 4];
  s8v v = *(s8v*)&vpT[base];
  v[0] = f2bf_s(bf2f_s(v[0]) / z0.x); v[1] = f2bf_s(bf2f_s(v[1]) / z0.y);
  v[2] = f2bf_s(bf2f_s(v[2]) / z0.z); v[3] = f2bf_s(bf2f_s(v[3]) / z0.w);
  v[4] = f2bf_s(bf2f_s(v[4]) / z1.x); v[5] = f2bf_s(bf2f_s(v[5]) / z1.y);
  v[6] = f2bf_s(bf2f_s(v[6]) / z1.z); v[7] = f2bf_s(bf2f_s(v[7]) / z1.w);
  *(s8v*)&vpT[base] = v;
}

extern "C" void kernel_launch(void* const* d_in, const int* in_sizes, int n_in,
                              void* d_out, int out_size, void* d_ws, size_t ws_size,
                              hipStream_t stream) {
  const float* q   = (const float*)d_in[0];
  const float* k   = (const float*)d_in[1];
  const float* v   = (const float*)d_in[2];
  const float* WQw = (const float*)d_in[3];
  const float* WQb = (const float*)d_in[4];
  const float* WKw = (const float*)d_in[5];
  const float* WKb = (const float*)d_in[6];
  const float* WVw = (const float*)d_in[7];
  const float* WVb = (const float*)d_in[8];

  char* ws = (char*)d_ws;
  // E occupies [0,32M); bf16 input/weight copies alias its head (dead before E written)
  short* E   = (short*)(ws);                 // 32 MB  [4][2048][2048]
  short* qb  = (short*)(ws);                 //  8 MB  [8192][512]  (qb,kb,vb contiguous)
  short* Wqb = (short*)(ws + 25165824);      // 3x 512 KB contiguous
  short* qp  = (short*)(ws + 33554432);      //  8 MB  [4][2048][512]
  short* kp  = (short*)(ws + 41943040);      //  8 MB
  short* vpT = (short*)(ws + 50331648);      //  8 MB  [4][512][2048]
  float* Z   = (float*)(ws + 58720256);      // 32 KB  [4][2048]
  short* kb  = qb + 4194304;
  short* vb  = qb + 8388608;
  short* Wkb = Wqb + 262144;
  short* Wvb = Wqb + 524288;

  const dim3 blk(256);

  hipMemsetAsync(Z, 0, 4 * S_LEN * sizeof(float), stream);

  cvt3<<<dim3(2048, 3), blk, 0, stream>>>(q, k, v, qb, 4194304);
  cvt3<<<dim3(128, 3), blk, 0, stream>>>(WQw, WKw, WVw, Wqb, 262144);

  // projections: M=8192, N=512, K=512 — one launch, 768 blocks
  proj3<<<dim3(4, 64, 3), blk, 0, stream>>>(
      qb, kb, vb, Wqb, Wkb, Wvb, qp, kp, vpT, WQb, WKb, WVb);

  // scores + mask + exp + fused column-sum: per batch M=N=2048, K=512
  gemm_scores<<<dim3(16, 16, 4), blk, 0, stream>>>(qp, kp, E, Z);

  // fold 1/Z into vp rows
  scale_vpt<<<dim3(2048), blk, 0, stream>>>(vpT, Z);

  // out = E @ vpT': 64x128 tiles, full K -> 512 blocks, no reduce
  gemm_out<<<dim3(4, 32, 4), blk, 0, stream>>>(E, vpT, (float*)d_out);
}

// Round 7
// 202.767 us; speedup vs baseline: 1.0182x; 1.0182x over previous
//
#include <hip/hip_runtime.h>
#include <hip/hip_bf16.h>

// B=4, S=2048, D=512. fp32 in/out, bf16 MFMA internals.
//   cvt: q,k,v,W* fp32 -> bf16
//   proj3: qp = q@WQ^T+b, kp = k@WK^T+b, vpT = (v@WV^T+b)^T  (one launch, z=0..2)
//   scores: E = exp(mask(scale*qp@kp^T)) bf16, masked(q<k)=1; fused Z[k]=sum_q E[q][k]
//   scale:  vpT[b][d][k] /= Z[b][k]
//   out:    E @ vpT^T -> fp32 d_out (64x128 tiles, full K)
// GEMM cores: BK=64 (half the barrier drains of BK=32), global_load_lds width-16
// staging, XOR(row&7) column-group swizzle -> ds_read_b128 at the structural
// 8-lanes-per-4-bank-group floor. bf16 row-major epilogues go through an LDS
// transpose (stride-68 pad) for 16B-coalesced stores.

#define S_LEN 2048
#define D_DIM 512
#define SCALE_F 0.044194173824159216f  // 1/sqrt(512)

typedef __attribute__((ext_vector_type(8))) short s8v;   // 8 bf16 = 4 VGPRs
typedef __attribute__((ext_vector_type(4))) short s4v;   // 4 bf16 = 8 B
typedef __attribute__((ext_vector_type(4))) float f4v;   // MFMA accumulator

enum { EPI_BIAS = 0, EPI_BIAS_T = 1, EPI_SCORES = 2 };

__device__ __forceinline__ short f2bf_s(float f) {
  union { __hip_bfloat16 b; short s; } u; u.b = __float2bfloat16(f); return u.s;
}
__device__ __forceinline__ float bf2f_s(short h) {
  union { short s; __hip_bfloat16 b; } u; u.s = h; return __bfloat162float(u.b);
}

__device__ __forceinline__ void glds16(const short* g, short* l) {
  __builtin_amdgcn_global_load_lds((const __attribute__((address_space(1))) void*)g,
                                   (__attribute__((address_space(3))) void*)l, 16, 0, 0);
}

// Core NT GEMM, 128x128 tile at (m0,n0), BK=64. A,B offset to batch.
// SMEM: 16384 shorts (As 128x64, Bs 128x64). bf16 epilogue reuses SMEM as
// per-wave 32x64 transpose buffers (stride 68).
template <int EPI>
__device__ __forceinline__ void gemm_core(
    const short* __restrict__ A, const short* __restrict__ B,
    short* __restrict__ C, const float* __restrict__ bias,
    short* SMEM, int N, int K, size_t sCz, int m0, int n0, int bz,
    float* __restrict__ Z)
{
  short* As = SMEM;
  short* Bs = SMEM + 8192;

  const int tid  = threadIdx.x;
  const int w    = tid >> 6;
  const int lane = tid & 63;
  const int quad = lane >> 4;
  const int l16  = lane & 15;
  const int wm   = (w >> 1) * 64;
  const int wn   = (w & 1) * 64;

  // staging: issue p covers rows p*32..p*32+31; thread t -> row p*32+(t>>3),
  // phys 16B slot t&7 holding logical column-group (t&7)^(row&7)
  const int strow = tid >> 3;                         // 0..31
  const int gl = ((tid & 7) ^ (strow & 7)) * 8;       // logical col offset (shorts)

  f4v acc[4][4];
#pragma unroll
  for (int i = 0; i < 4; ++i)
#pragma unroll
    for (int j = 0; j < 4; ++j)
#pragma unroll
      for (int r = 0; r < 4; ++r) acc[i][j][r] = 0.0f;

  const short* Ag = A + (size_t)(m0 + strow) * K + gl;
  const short* Bg = B + (size_t)(n0 + strow) * K + gl;
  short* Asl = As + tid * 8;
  short* Bsl = Bs + tid * 8;
  const size_t pstr = (size_t)32 * K;

  const int swq = l16 & 7;   // read-side swizzle = row&7

  for (int k0 = 0; k0 < K; k0 += 64) {
#pragma unroll
    for (int p = 0; p < 4; ++p) glds16(Ag + k0 + p * pstr, Asl + p * 2048);
#pragma unroll
    for (int p = 0; p < 4; ++p) glds16(Bg + k0 + p * pstr, Bsl + p * 2048);
    __syncthreads();

#pragma unroll
    for (int kk = 0; kk < 2; ++kk) {
      s8v af[4], bf[4];
#pragma unroll
      for (int i = 0; i < 4; ++i)
        af[i] = *(const s8v*)&As[(wm + i * 16 + l16) * 64 + (((kk * 4 + quad) ^ swq) * 8)];
#pragma unroll
      for (int j = 0; j < 4; ++j)
        bf[j] = *(const s8v*)&Bs[(wn + j * 16 + l16) * 64 + (((kk * 4 + quad) ^ swq) * 8)];
#pragma unroll
      for (int i = 0; i < 4; ++i)
#pragma unroll
        for (int j = 0; j < 4; ++j)
          acc[i][j] = __builtin_amdgcn_mfma_f32_16x16x32_bf16(af[i], bf[j], acc[i][j], 0, 0, 0);
    }
    __syncthreads();
  }

  // ---- epilogue ----
  float bv[4];
  if (EPI == EPI_BIAS || EPI == EPI_BIAS_T) {
#pragma unroll
    for (int j = 0; j < 4; ++j) bv[j] = bias[n0 + wn + j * 16 + l16];
  }

  if (EPI == EPI_BIAS_T) {
    // vpT[b][gn][ss]: 4 consecutive ss per lane -> one 8B store
#pragma unroll
    for (int i = 0; i < 4; ++i) {
#pragma unroll
      for (int j = 0; j < 4; ++j) {
        const int gn  = n0 + wn + j * 16 + l16;
        const int gmb = m0 + wm + i * 16 + quad * 4;
        const int bb = gmb >> 11, ssb = gmb & (S_LEN - 1);
        s4v o;
#pragma unroll
        for (int r = 0; r < 4; ++r) o[r] = f2bf_s(acc[i][j][r] + bv[j]);
        *(s4v*)&C[((size_t)bb * D_DIM + gn) * S_LEN + ssb] = o;
      }
    }
    return;
  }

  // EPI_BIAS / EPI_SCORES: LDS transpose -> coalesced 16B row stores.
  short* TB = SMEM;                 // 4 waves x 2176 shorts (32 rows x stride 68)
  const int wbase = w * 2176;
  float csum[4] = {0.f, 0.f, 0.f, 0.f};

#pragma unroll
  for (int ph = 0; ph < 2; ++ph) {
    __syncthreads();
#pragma unroll
    for (int ii = 0; ii < 2; ++ii) {
      const int i = ph * 2 + ii;
#pragma unroll
      for (int j = 0; j < 4; ++j) {
        const int gn = n0 + wn + j * 16 + l16;
#pragma unroll
        for (int r = 0; r < 4; ++r) {
          short o;
          if (EPI == EPI_SCORES) {
            const int gm = m0 + wm + i * 16 + quad * 4 + r;
            const float e = (gm >= gn) ? __expf(acc[i][j][r] * SCALE_F) : 1.0f;
            csum[j] += e;
            o = f2bf_s(e);
          } else {
            o = f2bf_s(acc[i][j][r] + bv[j]);
          }
          TB[wbase + (ii * 16 + quad * 4 + r) * 68 + j * 16 + l16] = o;
        }
      }
    }
    __syncthreads();
#pragma unroll
    for (int p = 0; p < 4; ++p) {
      const int row = p * 8 + (lane >> 3);   // 0..31
      const int cg  = lane & 7;
      const s8v vv = *(const s8v*)&TB[wbase + row * 68 + cg * 8];
      const int gm = m0 + wm + ph * 32 + row;
      const int gn = n0 + wn + cg * 8;
      *(s8v*)&C[sCz + (size_t)gm * N + gn] = vv;
    }
  }

  if (EPI == EPI_SCORES) {
#pragma unroll
    for (int j = 0; j < 4; ++j) {
      float cs = csum[j];
      cs += __shfl_xor(cs, 16, 64);
      cs += __shfl_xor(cs, 32, 64);
      if (quad == 0) atomicAdd(&Z[(bz << 11) + n0 + wn + j * 16 + l16], cs);
    }
  }
}

// scores kernel
__global__ __launch_bounds__(256, 2) void gemm_scores(
    const short* __restrict__ A, const short* __restrict__ B, short* __restrict__ C,
    float* __restrict__ Z)
{
  __shared__ __align__(16) short SMEM[16384];
  const int bz = blockIdx.z;
  gemm_core<EPI_SCORES>(A + (size_t)bz * S_LEN * D_DIM, B + (size_t)bz * S_LEN * D_DIM,
                        C, nullptr, SMEM, S_LEN, D_DIM,
                        (size_t)bz * S_LEN * S_LEN, blockIdx.y * 128, blockIdx.x * 128,
                        bz, Z);
}

// three projections in one launch: z=0 -> qp, z=1 -> kp, z=2 -> vpT (transposed)
__global__ __launch_bounds__(256, 2) void proj3(
    const short* __restrict__ a0, const short* __restrict__ a1, const short* __restrict__ a2,
    const short* __restrict__ b0, const short* __restrict__ b1, const short* __restrict__ b2,
    short* __restrict__ c0, short* __restrict__ c1, short* __restrict__ c2,
    const float* __restrict__ x0, const float* __restrict__ x1, const float* __restrict__ x2)
{
  __shared__ __align__(16) short SMEM[16384];
  const int z = blockIdx.z;
  const short* A = (z == 0) ? a0 : (z == 1) ? a1 : a2;
  const short* B = (z == 0) ? b0 : (z == 1) ? b1 : b2;
  short*       C = (z == 0) ? c0 : (z == 1) ? c1 : c2;
  const float* bias = (z == 0) ? x0 : (z == 1) ? x1 : x2;
  if (z == 2)
    gemm_core<EPI_BIAS_T>(A, B, C, bias, SMEM, D_DIM, D_DIM, 0,
                          blockIdx.y * 128, blockIdx.x * 128, 0, nullptr);
  else
    gemm_core<EPI_BIAS>(A, B, C, bias, SMEM, D_DIM, D_DIM, 0,
                        blockIdx.y * 128, blockIdx.x * 128, 0, nullptr);
}

// out = E @ vpT^T, per batch M=2048 N=512 K=2048, 64x128 tiles, BK=64, fp32 out
__global__ __launch_bounds__(256, 2) void gemm_out(
    const short* __restrict__ E, const short* __restrict__ vpT,
    float* __restrict__ out)
{
  __shared__ __align__(16) short As[64 * 64];    //  8 KB
  __shared__ __align__(16) short Bs[128 * 64];   // 16 KB

  const int tid  = threadIdx.x;
  const int bz   = blockIdx.z;
  const int m0   = blockIdx.y * 64;
  const int n0   = blockIdx.x * 128;

  const short* A = E   + (size_t)bz * S_LEN * S_LEN;
  const short* B = vpT + (size_t)bz * D_DIM * S_LEN;

  const int w    = tid >> 6;
  const int lane = tid & 63;
  const int quad = lane >> 4;
  const int l16  = lane & 15;
  const int wm   = (w >> 1) * 32;
  const int wn   = (w & 1) * 64;

  const int strow = tid >> 3;
  const int gl = ((tid & 7) ^ (strow & 7)) * 8;

  f4v acc[2][4];
#pragma unroll
  for (int i = 0; i < 2; ++i)
#pragma unroll
    for (int j = 0; j < 4; ++j)
#pragma unroll
      for (int r = 0; r < 4; ++r) acc[i][j][r] = 0.0f;

  const short* Ag = A + (size_t)(m0 + strow) * S_LEN + gl;
  const short* Bg = B + (size_t)(n0 + strow) * S_LEN + gl;
  short* Asl = As + tid * 8;
  short* Bsl = Bs + tid * 8;
  const size_t pstr = (size_t)32 * S_LEN;

  const int swq = l16 & 7;

  for (int k0 = 0; k0 < S_LEN; k0 += 64) {
#pragma unroll
    for (int p = 0; p < 2; ++p) glds16(Ag + k0 + p * pstr, Asl + p * 2048);
#pragma unroll
    for (int p = 0; p < 4; ++p) glds16(Bg + k0 + p * pstr, Bsl + p * 2048);
    __syncthreads();

#pragma unroll
    for (int kk = 0; kk < 2; ++kk) {
      s8v af[2], bf[4];
#pragma unroll
      for (int i = 0; i < 2; ++i)
        af[i] = *(const s8v*)&As[(wm + i * 16 + l16) * 64 + (((kk * 4 + quad) ^ swq) * 8)];
#pragma unroll
      for (int j = 0; j < 4; ++j)
        bf[j] = *(const s8v*)&Bs[(wn + j * 16 + l16) * 64 + (((kk * 4 + quad) ^ swq) * 8)];
#pragma unroll
      for (int i = 0; i < 2; ++i)
#pragma unroll
        for (int j = 0; j < 4; ++j)
          acc[i][j] = __builtin_amdgcn_mfma_f32_16x16x32_bf16(af[i], bf[j], acc[i][j], 0, 0, 0);
    }
    __syncthreads();
  }

  float* Cf = out + (size_t)bz * S_LEN * D_DIM;
#pragma unroll
  for (int i = 0; i < 2; ++i) {
#pragma unroll
    for (int j = 0; j < 4; ++j) {
      const int gn = n0 + wn + j * 16 + l16;
#pragma unroll
      for (int r = 0; r < 4; ++r) {
        const int gm = m0 + wm + i * 16 + quad * 4 + r;
        Cf[(size_t)gm * D_DIM + gn] = acc[i][j][r];
      }
    }
  }
}

// fp32 -> bf16, 8 elems/thread, three source arrays -> contiguous dst slabs
__global__ __launch_bounds__(256) void cvt3(
    const float* __restrict__ s0, const float* __restrict__ s1,
    const float* __restrict__ s2, short* __restrict__ dst, int n)
{
  const float* s = (blockIdx.y == 0) ? s0 : (blockIdx.y == 1) ? s1 : s2;
  short* d = dst + (size_t)blockIdx.y * n;
  const int i = (blockIdx.x * 256 + threadIdx.x) * 8;
  if (i >= n) return;
  const float4 f0 = *(const float4*)(s + i);
  const float4 f1 = *(const float4*)(s + i + 4);
  s8v o;
  o[0] = f2bf_s(f0.x); o[1] = f2bf_s(f0.y); o[2] = f2bf_s(f0.z); o[3] = f2bf_s(f0.w);
  o[4] = f2bf_s(f1.x); o[5] = f2bf_s(f1.y); o[6] = f2bf_s(f1.z); o[7] = f2bf_s(f1.w);
  *(s8v*)(d + i) = o;
}

// vpT[b][d][k] *= 1/Z[b][k], 8 consecutive k per thread
__global__ __launch_bounds__(256) void scale_vpt(
    short* __restrict__ vpT, const float* __restrict__ Z)
{
  const size_t base = ((size_t)blockIdx.x * 256 + threadIdx.x) * 8;  // < 2^22
  const int kk = (int)(base & (S_LEN - 1));
  const int b  = (int)(base >> 20);
  const float4 z0 = *(const float4*)&Z[(b << 11) + kk];
  const float4 z1 = *(const float4*)&Z[(b << 11) + kk + 4];
  s8v v = *(s8v*)&vpT[base];
  v[0] = f2bf_s(bf2f_s(v[0]) / z0.x); v[1] = f2bf_s(bf2f_s(v[1]) / z0.y);
  v[2] = f2bf_s(bf2f_s(v[2]) / z0.z); v[3] = f2bf_s(bf2f_s(v[3]) / z0.w);
  v[4] = f2bf_s(bf2f_s(v[4]) / z1.x); v[5] = f2bf_s(bf2f_s(v[5]) / z1.y);
  v[6] = f2bf_s(bf2f_s(v[6]) / z1.z); v[7] = f2bf_s(bf2f_s(v[7]) / z1.w);
  *(s8v*)&vpT[base] = v;
}

extern "C" void kernel_launch(void* const* d_in, const int* in_sizes, int n_in,
                              void* d_out, int out_size, void* d_ws, size_t ws_size,
                              hipStream_t stream) {
  const float* q   = (const float*)d_in[0];
  const float* k   = (const float*)d_in[1];
  const float* v   = (const float*)d_in[2];
  const float* WQw = (const float*)d_in[3];
  const float* WQb = (const float*)d_in[4];
  const float* WKw = (const float*)d_in[5];
  const float* WKb = (const float*)d_in[6];
  const float* WVw = (const float*)d_in[7];
  const float* WVb = (const float*)d_in[8];

  char* ws = (char*)d_ws;
  // E occupies [0,32M); bf16 input/weight copies alias its head (dead before E written)
  short* E   = (short*)(ws);                 // 32 MB  [4][2048][2048]
  short* qb  = (short*)(ws);                 //  8 MB  [8192][512]  (qb,kb,vb contiguous)
  short* Wqb = (short*)(ws + 25165824);      // 3x 512 KB contiguous
  short* qp  = (short*)(ws + 33554432);      //  8 MB  [4][2048][512]
  short* kp  = (short*)(ws + 41943040);      //  8 MB
  short* vpT = (short*)(ws + 50331648);      //  8 MB  [4][512][2048]
  float* Z   = (float*)(ws + 58720256);      // 32 KB  [4][2048]
  short* kb  = qb + 4194304;
  short* vb  = qb + 8388608;
  short* Wkb = Wqb + 262144;
  short* Wvb = Wqb + 524288;

  const dim3 blk(256);

  hipMemsetAsync(Z, 0, 4 * S_LEN * sizeof(float), stream);

  cvt3<<<dim3(2048, 3), blk, 0, stream>>>(q, k, v, qb, 4194304);
  cvt3<<<dim3(128, 3), blk, 0, stream>>>(WQw, WKw, WVw, Wqb, 262144);

  // projections: M=8192, N=512, K=512 — one launch, 768 blocks
  proj3<<<dim3(4, 64, 3), blk, 0, stream>>>(
      qb, kb, vb, Wqb, Wkb, Wvb, qp, kp, vpT, WQb, WKb, WVb);

  // scores + mask + exp + fused column-sum: per batch M=N=2048, K=512
  gemm_scores<<<dim3(16, 16, 4), blk, 0, stream>>>(qp, kp, E, Z);

  // fold 1/Z into vp rows
  scale_vpt<<<dim3(2048), blk, 0, stream>>>(vpT, Z);

  // out = E @ vpT': 64x128 tiles, BK=64, full K -> 512 blocks
  gemm_out<<<dim3(4, 32, 4), blk, 0, stream>>>(E, vpT, (float*)d_out);
}

// Round 8
// 198.250 us; speedup vs baseline: 1.0414x; 1.0228x over previous
//
#include <hip/hip_runtime.h>
#include <hip/hip_bf16.h>

// B=4, S=2048, D=512. fp32 in/out, bf16 MFMA internals.
//   cvt: q,k,v,W* fp32 -> bf16
//   proj3: qp = q@WQ^T+b, kp = k@WK^T+b, vpT = (v@WV^T+b)^T  (one launch, z=0..2)
//   scores: E = exp(mask(scale*qp@kp^T)) bf16, masked(q<k)=1; fused Z[k]=sum_q E[q][k]
//   scale:  vpT[b][d][k] /= Z[b][k]
//   out:    E @ vpT^T -> fp32 d_out (64x128 tiles, BK=64, triple-buffered)
// K-loops use AITER-style cross-barrier prefetch: multi-buffered LDS,
// global_load_lds kept in flight across raw `s_barrier`s, drained with
// fine-grained `s_waitcnt vmcnt(N)` (never 0 except the last iteration).
// XOR(row&7) column-group swizzle keeps ds_read_b128 conflict-free (verified:
// SQ_LDS_BANK_CONFLICT == 0 in round 7).

#define S_LEN 2048
#define D_DIM 512
#define SCALE_F 0.044194173824159216f  // 1/sqrt(512)

typedef __attribute__((ext_vector_type(8))) short s8v;   // 8 bf16 = 4 VGPRs
typedef __attribute__((ext_vector_type(4))) short s4v;   // 4 bf16 = 8 B
typedef __attribute__((ext_vector_type(4))) float f4v;   // MFMA accumulator

enum { EPI_BIAS = 0, EPI_BIAS_T = 1, EPI_SCORES = 2 };

#define SBAR()    asm volatile("s_barrier" ::: "memory")
#define WAITV(n)  asm volatile("s_waitcnt vmcnt(" #n ")" ::: "memory")

__device__ __forceinline__ short f2bf_s(float f) {
  union { __hip_bfloat16 b; short s; } u; u.b = __float2bfloat16(f); return u.s;
}
__device__ __forceinline__ float bf2f_s(short h) {
  union { short s; __hip_bfloat16 b; } u; u.s = h; return __bfloat162float(u.b);
}

__device__ __forceinline__ void glds16(const short* g, short* l) {
  __builtin_amdgcn_global_load_lds((const __attribute__((address_space(1))) void*)g,
                                   (__attribute__((address_space(3))) void*)l, 16, 0, 0);
}

// Core NT GEMM, 128x128 tile at (m0,n0), BK=64, double-buffered LDS.
// SMEM layout: buf c at c*16384; As = +0 (128x64), Bs = +8192 (128x64). shorts.
// bf16 epilogues reuse SMEM as per-wave 32x64 transpose buffers (stride 68).
template <int EPI>
__device__ __forceinline__ void gemm_core(
    const short* __restrict__ A, const short* __restrict__ B,
    short* __restrict__ C, const float* __restrict__ bias,
    short* SMEM, int N, int K, size_t sCz, int m0, int n0, int bz,
    float* __restrict__ Z)
{
  const int tid  = threadIdx.x;
  const int w    = tid >> 6;
  const int lane = tid & 63;
  const int quad = lane >> 4;
  const int l16  = lane & 15;
  const int wm   = (w >> 1) * 64;
  const int wn   = (w & 1) * 64;

  // staging: issue p covers rows p*32..p*32+31; thread t -> row p*32+(t>>3),
  // phys 16B slot t&7 holding logical column-group (t&7)^(row&7)
  const int strow = tid >> 3;                         // 0..31
  const int gl = ((tid & 7) ^ (strow & 7)) * 8;       // logical col offset (shorts)

  f4v acc[4][4];
#pragma unroll
  for (int i = 0; i < 4; ++i)
#pragma unroll
    for (int j = 0; j < 4; ++j)
#pragma unroll
      for (int r = 0; r < 4; ++r) acc[i][j][r] = 0.0f;

  const short* Ag = A + (size_t)(m0 + strow) * K + gl;
  const short* Bg = B + (size_t)(n0 + strow) * K + gl;
  const size_t pstr = (size_t)32 * K;
  const int t8 = tid * 8;
  const int swq = l16 & 7;   // read-side swizzle = row&7

  const int niter = K >> 6;

  // preload iter 0 into buf0 (8 loads)
#pragma unroll
  for (int p = 0; p < 4; ++p) glds16(Ag + p * pstr, SMEM + t8 + p * 2048);
#pragma unroll
  for (int p = 0; p < 4; ++p) glds16(Bg + p * pstr, SMEM + 8192 + t8 + p * 2048);

  for (int i = 0; i < niter; ++i) {
    const int c = i & 1;
    if (i + 1 < niter) {
      const int k1 = (i + 1) << 6;
      short* dA = SMEM + (1 - c) * 16384 + t8;
#pragma unroll
      for (int p = 0; p < 4; ++p) glds16(Ag + k1 + p * pstr, dA + p * 2048);
#pragma unroll
      for (int p = 0; p < 4; ++p) glds16(Bg + k1 + p * pstr, dA + 8192 + p * 2048);
      WAITV(8);       // drain iter i's 8 loads, leave prefetch in flight
    } else {
      WAITV(0);
    }
    SBAR();

    const short* As = SMEM + c * 16384;
    const short* Bs = As + 8192;
#pragma unroll
    for (int kk = 0; kk < 2; ++kk) {
      s8v af[4], bf[4];
#pragma unroll
      for (int ii = 0; ii < 4; ++ii)
        af[ii] = *(const s8v*)&As[(wm + ii * 16 + l16) * 64 + (((kk * 4 + quad) ^ swq) * 8)];
#pragma unroll
      for (int j = 0; j < 4; ++j)
        bf[j] = *(const s8v*)&Bs[(wn + j * 16 + l16) * 64 + (((kk * 4 + quad) ^ swq) * 8)];
#pragma unroll
      for (int ii = 0; ii < 4; ++ii)
#pragma unroll
        for (int j = 0; j < 4; ++j)
          acc[ii][j] = __builtin_amdgcn_mfma_f32_16x16x32_bf16(af[ii], bf[j], acc[ii][j], 0, 0, 0);
    }
    SBAR();           // protect buf[c] before its rewrite next iteration
  }

  // ---- epilogue ----
  float bv[4];
  if (EPI == EPI_BIAS || EPI == EPI_BIAS_T) {
#pragma unroll
    for (int j = 0; j < 4; ++j) bv[j] = bias[n0 + wn + j * 16 + l16];
  }

  if (EPI == EPI_BIAS_T) {
    // vpT[b][gn][ss]: 4 consecutive ss per lane -> one 8B store
#pragma unroll
    for (int i = 0; i < 4; ++i) {
#pragma unroll
      for (int j = 0; j < 4; ++j) {
        const int gn  = n0 + wn + j * 16 + l16;
        const int gmb = m0 + wm + i * 16 + quad * 4;
        const int bb = gmb >> 11, ssb = gmb & (S_LEN - 1);
        s4v o;
#pragma unroll
        for (int r = 0; r < 4; ++r) o[r] = f2bf_s(acc[i][j][r] + bv[j]);
        *(s4v*)&C[((size_t)bb * D_DIM + gn) * S_LEN + ssb] = o;
      }
    }
    return;
  }

  // EPI_BIAS / EPI_SCORES: LDS transpose -> coalesced 16B row stores.
  short* TB = SMEM;                 // 4 waves x 2176 shorts (32 rows x stride 68)
  const int wbase = w * 2176;
  float csum[4] = {0.f, 0.f, 0.f, 0.f};

#pragma unroll
  for (int ph = 0; ph < 2; ++ph) {
    __syncthreads();
#pragma unroll
    for (int ii = 0; ii < 2; ++ii) {
      const int i = ph * 2 + ii;
#pragma unroll
      for (int j = 0; j < 4; ++j) {
        const int gn = n0 + wn + j * 16 + l16;
#pragma unroll
        for (int r = 0; r < 4; ++r) {
          short o;
          if (EPI == EPI_SCORES) {
            const int gm = m0 + wm + i * 16 + quad * 4 + r;
            const float e = (gm >= gn) ? __expf(acc[i][j][r] * SCALE_F) : 1.0f;
            csum[j] += e;
            o = f2bf_s(e);
          } else {
            o = f2bf_s(acc[i][j][r] + bv[j]);
          }
          TB[wbase + (ii * 16 + quad * 4 + r) * 68 + j * 16 + l16] = o;
        }
      }
    }
    __syncthreads();
#pragma unroll
    for (int p = 0; p < 4; ++p) {
      const int row = p * 8 + (lane >> 3);   // 0..31
      const int cg  = lane & 7;
      const s8v vv = *(const s8v*)&TB[wbase + row * 68 + cg * 8];
      const int gm = m0 + wm + ph * 32 + row;
      const int gn = n0 + wn + cg * 8;
      *(s8v*)&C[sCz + (size_t)gm * N + gn] = vv;
    }
  }

  if (EPI == EPI_SCORES) {
#pragma unroll
    for (int j = 0; j < 4; ++j) {
      float cs = csum[j];
      cs += __shfl_xor(cs, 16, 64);
      cs += __shfl_xor(cs, 32, 64);
      if (quad == 0) atomicAdd(&Z[(bz << 11) + n0 + wn + j * 16 + l16], cs);
    }
  }
}

// scores kernel
__global__ __launch_bounds__(256, 2) void gemm_scores(
    const short* __restrict__ A, const short* __restrict__ B, short* __restrict__ C,
    float* __restrict__ Z)
{
  __shared__ __align__(16) short SMEM[32768];   // 64 KB: 2 x (As 128x64 + Bs 128x64)
  const int bz = blockIdx.z;
  gemm_core<EPI_SCORES>(A + (size_t)bz * S_LEN * D_DIM, B + (size_t)bz * S_LEN * D_DIM,
                        C, nullptr, SMEM, S_LEN, D_DIM,
                        (size_t)bz * S_LEN * S_LEN, blockIdx.y * 128, blockIdx.x * 128,
                        bz, Z);
}

// three projections in one launch: z=0 -> qp, z=1 -> kp, z=2 -> vpT (transposed)
__global__ __launch_bounds__(256, 2) void proj3(
    const short* __restrict__ a0, const short* __restrict__ a1, const short* __restrict__ a2,
    const short* __restrict__ b0, const short* __restrict__ b1, const short* __restrict__ b2,
    short* __restrict__ c0, short* __restrict__ c1, short* __restrict__ c2,
    const float* __restrict__ x0, const float* __restrict__ x1, const float* __restrict__ x2)
{
  __shared__ __align__(16) short SMEM[32768];
  const int z = blockIdx.z;
  const short* A = (z == 0) ? a0 : (z == 1) ? a1 : a2;
  const short* B = (z == 0) ? b0 : (z == 1) ? b1 : b2;
  short*       C = (z == 0) ? c0 : (z == 1) ? c1 : c2;
  const float* bias = (z == 0) ? x0 : (z == 1) ? x1 : x2;
  if (z == 2)
    gemm_core<EPI_BIAS_T>(A, B, C, bias, SMEM, D_DIM, D_DIM, 0,
                          blockIdx.y * 128, blockIdx.x * 128, 0, nullptr);
  else
    gemm_core<EPI_BIAS>(A, B, C, bias, SMEM, D_DIM, D_DIM, 0,
                        blockIdx.y * 128, blockIdx.x * 128, 0, nullptr);
}

// out = E @ vpT^T, per batch M=2048 N=512 K=2048, 64x128 tiles, BK=64,
// triple-buffered, prefetch depth 2, fp32 out.
// SMEM: buf c at c*12288; As = +0 (64x64), Bs = +4096 (128x64). shorts.
__global__ __launch_bounds__(256, 2) void gemm_out(
    const short* __restrict__ E, const short* __restrict__ vpT,
    float* __restrict__ out)
{
  __shared__ __align__(16) short SMEM[36864];   // 72 KB

  const int tid  = threadIdx.x;
  const int bz   = blockIdx.z;
  const int m0   = blockIdx.y * 64;
  const int n0   = blockIdx.x * 128;

  const short* A = E   + (size_t)bz * S_LEN * S_LEN;
  const short* B = vpT + (size_t)bz * D_DIM * S_LEN;

  const int w    = tid >> 6;
  const int lane = tid & 63;
  const int quad = lane >> 4;
  const int l16  = lane & 15;
  const int wm   = (w >> 1) * 32;
  const int wn   = (w & 1) * 64;

  const int strow = tid >> 3;
  const int gl = ((tid & 7) ^ (strow & 7)) * 8;

  f4v acc[2][4];
#pragma unroll
  for (int i = 0; i < 2; ++i)
#pragma unroll
    for (int j = 0; j < 4; ++j)
#pragma unroll
      for (int r = 0; r < 4; ++r) acc[i][j][r] = 0.0f;

  const short* Ag = A + (size_t)(m0 + strow) * S_LEN + gl;
  const short* Bg = B + (size_t)(n0 + strow) * S_LEN + gl;
  const size_t pstr = (size_t)32 * S_LEN;
  const int t8 = tid * 8;
  const int swq = l16 & 7;

  const int niter = S_LEN >> 6;   // 32

  // preload iters 0,1 into buf0,buf1 (6 loads each)
#pragma unroll
  for (int pre = 0; pre < 2; ++pre) {
    short* dst = SMEM + pre * 12288 + t8;
    const int k0 = pre << 6;
#pragma unroll
    for (int p = 0; p < 2; ++p) glds16(Ag + k0 + p * pstr, dst + p * 2048);
#pragma unroll
    for (int p = 0; p < 4; ++p) glds16(Bg + k0 + p * pstr, dst + 4096 + p * 2048);
  }

  int cbuf = 0, nbuf = 2;
  for (int i = 0; i < niter; ++i) {
    if (i + 2 < niter) {
      const int k2 = (i + 2) << 6;
      short* dst = SMEM + nbuf * 12288 + t8;
#pragma unroll
      for (int p = 0; p < 2; ++p) glds16(Ag + k2 + p * pstr, dst + p * 2048);
#pragma unroll
      for (int p = 0; p < 4; ++p) glds16(Bg + k2 + p * pstr, dst + 4096 + p * 2048);
      nbuf = (nbuf == 2) ? 0 : nbuf + 1;
      WAITV(12);      // 18 in flight; drain oldest 6 (iter i)
    } else if (i + 1 < niter) {
      WAITV(6);       // 12 in flight; drain iter i
    } else {
      WAITV(0);
    }
    SBAR();

    const short* As = SMEM + cbuf * 12288;
    const short* Bs = As + 4096;
    cbuf = (cbuf == 2) ? 0 : cbuf + 1;
#pragma unroll
    for (int kk = 0; kk < 2; ++kk) {
      s8v af[2], bf[4];
#pragma unroll
      for (int ii = 0; ii < 2; ++ii)
        af[ii] = *(const s8v*)&As[(wm + ii * 16 + l16) * 64 + (((kk * 4 + quad) ^ swq) * 8)];
#pragma unroll
      for (int j = 0; j < 4; ++j)
        bf[j] = *(const s8v*)&Bs[(wn + j * 16 + l16) * 64 + (((kk * 4 + quad) ^ swq) * 8)];
#pragma unroll
      for (int ii = 0; ii < 2; ++ii)
#pragma unroll
        for (int j = 0; j < 4; ++j)
          acc[ii][j] = __builtin_amdgcn_mfma_f32_16x16x32_bf16(af[ii], bf[j], acc[ii][j], 0, 0, 0);
    }
    SBAR();           // protect the buffer rewritten next iteration
  }

  float* Cf = out + (size_t)bz * S_LEN * D_DIM;
#pragma unroll
  for (int i = 0; i < 2; ++i) {
#pragma unroll
    for (int j = 0; j < 4; ++j) {
      const int gn = n0 + wn + j * 16 + l16;
#pragma unroll
      for (int r = 0; r < 4; ++r) {
        const int gm = m0 + wm + i * 16 + quad * 4 + r;
        Cf[(size_t)gm * D_DIM + gn] = acc[i][j][r];
      }
    }
  }
}

// fp32 -> bf16, 8 elems/thread, three source arrays -> contiguous dst slabs
__global__ __launch_bounds__(256) void cvt3(
    const float* __restrict__ s0, const float* __restrict__ s1,
    const float* __restrict__ s2, short* __restrict__ dst, int n)
{
  const float* s = (blockIdx.y == 0) ? s0 : (blockIdx.y == 1) ? s1 : s2;
  short* d = dst + (size_t)blockIdx.y * n;
  const int i = (blockIdx.x * 256 + threadIdx.x) * 8;
  if (i >= n) return;
  const float4 f0 = *(const float4*)(s + i);
  const float4 f1 = *(const float4*)(s + i + 4);
  s8v o;
  o[0] = f2bf_s(f0.x); o[1] = f2bf_s(f0.y); o[2] = f2bf_s(f0.z); o[3] = f2bf_s(f0.w);
  o[4] = f2bf_s(f1.x); o[5] = f2bf_s(f1.y); o[6] = f2bf_s(f1.z); o[7] = f2bf_s(f1.w);
  *(s8v*)(d + i) = o;
}

// vpT[b][d][k] *= 1/Z[b][k], 8 consecutive k per thread
__global__ __launch_bounds__(256) void scale_vpt(
    short* __restrict__ vpT, const float* __restrict__ Z)
{
  const size_t base = ((size_t)blockIdx.x * 256 + threadIdx.x) * 8;  // < 2^22
  const int kk = (int)(base & (S_LEN - 1));
  const int b  = (int)(base >> 20);
  const float4 z0 = *(const float4*)&Z[(b << 11) + kk];
  const float4 z1 = *(const float4*)&Z[(b << 11) + kk + 4];
  s8v v = *(s8v*)&vpT[base];
  v[0] = f2bf_s(bf2f_s(v[0]) / z0.x); v[1] = f2bf_s(bf2f_s(v[1]) / z0.y);
  v[2] = f2bf_s(bf2f_s(v[2]) / z0.z); v[3] = f2bf_s(bf2f_s(v[3]) / z0.w);
  v[4] = f2bf_s(bf2f_s(v[4]) / z1.x); v[5] = f2bf_s(bf2f_s(v[5]) / z1.y);
  v[6] = f2bf_s(bf2f_s(v[6]) / z1.z); v[7] = f2bf_s(bf2f_s(v[7]) / z1.w);
  *(s8v*)&vpT[base] = v;
}

extern "C" void kernel_launch(void* const* d_in, const int* in_sizes, int n_in,
                              void* d_out, int out_size, void* d_ws, size_t ws_size,
                              hipStream_t stream) {
  const float* q   = (const float*)d_in[0];
  const float* k   = (const float*)d_in[1];
  const float* v   = (const float*)d_in[2];
  const float* WQw = (const float*)d_in[3];
  const float* WQb = (const float*)d_in[4];
  const float* WKw = (const float*)d_in[5];
  const float* WKb = (const float*)d_in[6];
  const float* WVw = (const float*)d_in[7];
  const float* WVb = (const float*)d_in[8];

  char* ws = (char*)d_ws;
  // E occupies [0,32M); bf16 input/weight copies alias its head (dead before E written)
  short* E   = (short*)(ws);                 // 32 MB  [4][2048][2048]
  short* qb  = (short*)(ws);                 //  8 MB  [8192][512]  (qb,kb,vb contiguous)
  short* Wqb = (short*)(ws + 25165824);      // 3x 512 KB contiguous
  short* qp  = (short*)(ws + 33554432);      //  8 MB  [4][2048][512]
  short* kp  = (short*)(ws + 41943040);      //  8 MB
  short* vpT = (short*)(ws + 50331648);      //  8 MB  [4][512][2048]
  float* Z   = (float*)(ws + 58720256);      // 32 KB  [4][2048]
  short* kb  = qb + 4194304;
  short* vb  = qb + 8388608;
  short* Wkb = Wqb + 262144;
  short* Wvb = Wqb + 524288;

  const dim3 blk(256);

  hipMemsetAsync(Z, 0, 4 * S_LEN * sizeof(float), stream);

  cvt3<<<dim3(2048, 3), blk, 0, stream>>>(q, k, v, qb, 4194304);
  cvt3<<<dim3(128, 3), blk, 0, stream>>>(WQw, WKw, WVw, Wqb, 262144);

  // projections: M=8192, N=512, K=512 — one launch, 768 blocks
  proj3<<<dim3(4, 64, 3), blk, 0, stream>>>(
      qb, kb, vb, Wqb, Wkb, Wvb, qp, kp, vpT, WQb, WKb, WVb);

  // scores + mask + exp + fused column-sum: per batch M=N=2048, K=512
  gemm_scores<<<dim3(16, 16, 4), blk, 0, stream>>>(qp, kp, E, Z);

  // fold 1/Z into vp rows
  scale_vpt<<<dim3(2048), blk, 0, stream>>>(vpT, Z);

  // out = E @ vpT': 64x128 tiles, BK=64, triple-buffered -> 512 blocks
  gemm_out<<<dim3(4, 32, 4), blk, 0, stream>>>(E, vpT, (float*)d_out);
}

// Round 9
// 183.237 us; speedup vs baseline: 1.1267x; 1.0819x over previous
//
#include <hip/hip_runtime.h>
#include <hip/hip_bf16.h>

// B=4, S=2048, D=512. fp32 in/out, bf16 MFMA internals.
// Key identity: multiplicative causal mask => E = 1 + F, F = expm1(scale*s) on
// the lower triangle (q>=k), 0 above. Then
//   out  = F @ vp'  +  T,   T[b,d] = sum_k vp'[b,k,d]
//   Z[k] = 2048 + colsum(F)
// so the scores GEMM runs only lower-triangular tiles (53%) and the out GEMM
// truncates K at m0+64 (52%).
// Pipeline:
//   cvt: q,k,v,W* fp32 -> bf16
//   proj3: qp,kp,vpT (one launch)
//   scoresF: F tiles (tri), fused ZF colsum
//   scaleT: vpT /= (2048+ZF), T = rowsum (fp32)
//   outF: F @ vpT'^T + T -> fp32 d_out (64x128, K-trunc, triple-buffered)

#define S_LEN 2048
#define D_DIM 512
#define SCALE_F 0.044194173824159216f  // 1/sqrt(512)

typedef __attribute__((ext_vector_type(8))) short s8v;   // 8 bf16 = 4 VGPRs
typedef __attribute__((ext_vector_type(4))) short s4v;   // 4 bf16 = 8 B
typedef __attribute__((ext_vector_type(4))) float f4v;   // MFMA accumulator

enum { EPI_BIAS = 0, EPI_BIAS_T = 1, EPI_SCORES = 2 };

#define SBAR()    asm volatile("s_barrier" ::: "memory")
#define WAITV(n)  asm volatile("s_waitcnt vmcnt(" #n ")" ::: "memory")

__device__ __forceinline__ short f2bf_s(float f) {
  union { __hip_bfloat16 b; short s; } u; u.b = __float2bfloat16(f); return u.s;
}
__device__ __forceinline__ float bf2f_s(short h) {
  union { short s; __hip_bfloat16 b; } u; u.s = h; return __bfloat162float(u.b);
}

__device__ __forceinline__ void glds16(const short* g, short* l) {
  __builtin_amdgcn_global_load_lds((const __attribute__((address_space(1))) void*)g,
                                   (__attribute__((address_space(3))) void*)l, 16, 0, 0);
}

// Core NT GEMM, 128x128 tile at (m0,n0), BK=64, double-buffered LDS.
// SMEM: buf c at c*16384; As=+0 (128x64), Bs=+8192. shorts.
template <int EPI>
__device__ __forceinline__ void gemm_core(
    const short* __restrict__ A, const short* __restrict__ B,
    short* __restrict__ C, const float* __restrict__ bias,
    short* SMEM, int N, int K, size_t sCz, int m0, int n0, int bz,
    float* __restrict__ Z)
{
  const int tid  = threadIdx.x;
  const int w    = tid >> 6;
  const int lane = tid & 63;
  const int quad = lane >> 4;
  const int l16  = lane & 15;
  const int wm   = (w >> 1) * 64;
  const int wn   = (w & 1) * 64;

  const int strow = tid >> 3;                         // 0..31
  const int gl = ((tid & 7) ^ (strow & 7)) * 8;       // XOR column-group swizzle

  f4v acc[4][4];
#pragma unroll
  for (int i = 0; i < 4; ++i)
#pragma unroll
    for (int j = 0; j < 4; ++j)
#pragma unroll
      for (int r = 0; r < 4; ++r) acc[i][j][r] = 0.0f;

  const short* Ag = A + (size_t)(m0 + strow) * K + gl;
  const short* Bg = B + (size_t)(n0 + strow) * K + gl;
  const size_t pstr = (size_t)32 * K;
  const int t8 = tid * 8;
  const int swq = l16 & 7;

  const int niter = K >> 6;

#pragma unroll
  for (int p = 0; p < 4; ++p) glds16(Ag + p * pstr, SMEM + t8 + p * 2048);
#pragma unroll
  for (int p = 0; p < 4; ++p) glds16(Bg + p * pstr, SMEM + 8192 + t8 + p * 2048);

  for (int i = 0; i < niter; ++i) {
    const int c = i & 1;
    if (i + 1 < niter) {
      const int k1 = (i + 1) << 6;
      short* dA = SMEM + (1 - c) * 16384 + t8;
#pragma unroll
      for (int p = 0; p < 4; ++p) glds16(Ag + k1 + p * pstr, dA + p * 2048);
#pragma unroll
      for (int p = 0; p < 4; ++p) glds16(Bg + k1 + p * pstr, dA + 8192 + p * 2048);
      WAITV(8);
    } else {
      WAITV(0);
    }
    SBAR();

    const short* As = SMEM + c * 16384;
    const short* Bs = As + 8192;
#pragma unroll
    for (int kk = 0; kk < 2; ++kk) {
      s8v af[4], bf[4];
#pragma unroll
      for (int ii = 0; ii < 4; ++ii)
        af[ii] = *(const s8v*)&As[(wm + ii * 16 + l16) * 64 + (((kk * 4 + quad) ^ swq) * 8)];
#pragma unroll
      for (int j = 0; j < 4; ++j)
        bf[j] = *(const s8v*)&Bs[(wn + j * 16 + l16) * 64 + (((kk * 4 + quad) ^ swq) * 8)];
#pragma unroll
      for (int ii = 0; ii < 4; ++ii)
#pragma unroll
        for (int j = 0; j < 4; ++j)
          acc[ii][j] = __builtin_amdgcn_mfma_f32_16x16x32_bf16(af[ii], bf[j], acc[ii][j], 0, 0, 0);
    }
    SBAR();
  }

  // ---- epilogue ----
  float bv[4];
  if (EPI == EPI_BIAS || EPI == EPI_BIAS_T) {
#pragma unroll
    for (int j = 0; j < 4; ++j) bv[j] = bias[n0 + wn + j * 16 + l16];
  }

  if (EPI == EPI_BIAS_T) {
#pragma unroll
    for (int i = 0; i < 4; ++i) {
#pragma unroll
      for (int j = 0; j < 4; ++j) {
        const int gn  = n0 + wn + j * 16 + l16;
        const int gmb = m0 + wm + i * 16 + quad * 4;
        const int bb = gmb >> 11, ssb = gmb & (S_LEN - 1);
        s4v o;
#pragma unroll
        for (int r = 0; r < 4; ++r) o[r] = f2bf_s(acc[i][j][r] + bv[j]);
        *(s4v*)&C[((size_t)bb * D_DIM + gn) * S_LEN + ssb] = o;
      }
    }
    return;
  }

  // EPI_BIAS / EPI_SCORES: LDS transpose -> coalesced 16B row stores.
  // EPI_SCORES writes F = expm1(scale*v) on q>=k, 0 above; csum accumulates F.
  short* TB = SMEM;                 // 4 waves x 2176 shorts (32 rows x stride 68)
  const int wbase = w * 2176;
  float csum[4] = {0.f, 0.f, 0.f, 0.f};

#pragma unroll
  for (int ph = 0; ph < 2; ++ph) {
    __syncthreads();
#pragma unroll
    for (int ii = 0; ii < 2; ++ii) {
      const int i = ph * 2 + ii;
#pragma unroll
      for (int j = 0; j < 4; ++j) {
        const int gn = n0 + wn + j * 16 + l16;
#pragma unroll
        for (int r = 0; r < 4; ++r) {
          short o;
          if (EPI == EPI_SCORES) {
            const int gm = m0 + wm + i * 16 + quad * 4 + r;
            const float f = (gm >= gn) ? (__expf(acc[i][j][r] * SCALE_F) - 1.0f) : 0.0f;
            csum[j] += f;
            o = f2bf_s(f);
          } else {
            o = f2bf_s(acc[i][j][r] + bv[j]);
          }
          TB[wbase + (ii * 16 + quad * 4 + r) * 68 + j * 16 + l16] = o;
        }
      }
    }
    __syncthreads();
#pragma unroll
    for (int p = 0; p < 4; ++p) {
      const int row = p * 8 + (lane >> 3);   // 0..31
      const int cg  = lane & 7;
      const s8v vv = *(const s8v*)&TB[wbase + row * 68 + cg * 8];
      const int gm = m0 + wm + ph * 32 + row;
      const int gn = n0 + wn + cg * 8;
      *(s8v*)&C[sCz + (size_t)gm * N + gn] = vv;
    }
  }

  if (EPI == EPI_SCORES) {
#pragma unroll
    for (int j = 0; j < 4; ++j) {
      float cs = csum[j];
      cs += __shfl_xor(cs, 16, 64);
      cs += __shfl_xor(cs, 32, 64);
      if (quad == 0) atomicAdd(&Z[(bz << 11) + n0 + wn + j * 16 + l16], cs);
    }
  }
}

// scores-F kernel: compact triangular grid, blockIdx.x in [0,136), z=batch.
__global__ __launch_bounds__(256, 2) void gemm_scoresF(
    const short* __restrict__ A, const short* __restrict__ B, short* __restrict__ C,
    float* __restrict__ Z)
{
  __shared__ __align__(16) short SMEM[32768];   // 64 KB
  const int bz = blockIdx.z;
  const int t = blockIdx.x;
  int ti = (int)((sqrtf(8.0f * t + 1.0f) - 1.0f) * 0.5f);
  while ((ti + 1) * (ti + 2) / 2 <= t) ++ti;
  while (ti * (ti + 1) / 2 > t) --ti;
  const int tj = t - ti * (ti + 1) / 2;         // tj <= ti
  gemm_core<EPI_SCORES>(A + (size_t)bz * S_LEN * D_DIM, B + (size_t)bz * S_LEN * D_DIM,
                        C, nullptr, SMEM, S_LEN, D_DIM,
                        (size_t)bz * S_LEN * S_LEN, ti * 128, tj * 128, bz, Z);
}

// three projections in one launch: z=0 -> qp, z=1 -> kp, z=2 -> vpT (transposed)
__global__ __launch_bounds__(256, 2) void proj3(
    const short* __restrict__ a0, const short* __restrict__ a1, const short* __restrict__ a2,
    const short* __restrict__ b0, const short* __restrict__ b1, const short* __restrict__ b2,
    short* __restrict__ c0, short* __restrict__ c1, short* __restrict__ c2,
    const float* __restrict__ x0, const float* __restrict__ x1, const float* __restrict__ x2)
{
  __shared__ __align__(16) short SMEM[32768];
  const int z = blockIdx.z;
  const short* A = (z == 0) ? a0 : (z == 1) ? a1 : a2;
  const short* B = (z == 0) ? b0 : (z == 1) ? b1 : b2;
  short*       C = (z == 0) ? c0 : (z == 1) ? c1 : c2;
  const float* bias = (z == 0) ? x0 : (z == 1) ? x1 : x2;
  if (z == 2)
    gemm_core<EPI_BIAS_T>(A, B, C, bias, SMEM, D_DIM, D_DIM, 0,
                          blockIdx.y * 128, blockIdx.x * 128, 0, nullptr);
  else
    gemm_core<EPI_BIAS>(A, B, C, bias, SMEM, D_DIM, D_DIM, 0,
                        blockIdx.y * 128, blockIdx.x * 128, 0, nullptr);
}

// out = F @ vpT'^T + T, 64x128 tiles, K truncated at m0+64, triple-buffered.
// SMEM: buf c at c*12288; As=+0 (64x64), Bs=+4096 (128x64).
__global__ __launch_bounds__(256, 2) void gemm_outF(
    const short* __restrict__ F, const short* __restrict__ vpT,
    const float* __restrict__ Tv, float* __restrict__ out)
{
  __shared__ __align__(16) short SMEM[36864];   // 72 KB

  const int tid  = threadIdx.x;
  const int bz   = blockIdx.z;
  const int m0   = (31 - blockIdx.y) * 64;      // longest blocks dispatch first
  const int n0   = blockIdx.x * 128;

  const short* A = F   + (size_t)bz * S_LEN * S_LEN;
  const short* B = vpT + (size_t)bz * D_DIM * S_LEN;

  const int w    = tid >> 6;
  const int lane = tid & 63;
  const int quad = lane >> 4;
  const int l16  = lane & 15;
  const int wm   = (w >> 1) * 32;
  const int wn   = (w & 1) * 64;

  const int strow = tid >> 3;
  const int gl = ((tid & 7) ^ (strow & 7)) * 8;

  f4v acc[2][4];
#pragma unroll
  for (int i = 0; i < 2; ++i)
#pragma unroll
    for (int j = 0; j < 4; ++j)
#pragma unroll
      for (int r = 0; r < 4; ++r) acc[i][j][r] = 0.0f;

  const short* Ag = A + (size_t)(m0 + strow) * S_LEN + gl;
  const short* Bg = B + (size_t)(n0 + strow) * S_LEN + gl;
  const size_t pstr = (size_t)32 * S_LEN;
  const int t8 = tid * 8;
  const int swq = l16 & 7;

  const int niter = (m0 >> 6) + 1;   // K runs 0 .. m0+64

  // preload iters 0,1 into buf0,buf1 (iter1 may read unmaterialized ws: unused)
#pragma unroll
  for (int pre = 0; pre < 2; ++pre) {
    short* dst = SMEM + pre * 12288 + t8;
    const int k0 = pre << 6;
#pragma unroll
    for (int p = 0; p < 2; ++p) glds16(Ag + k0 + p * pstr, dst + p * 2048);
#pragma unroll
    for (int p = 0; p < 4; ++p) glds16(Bg + k0 + p * pstr, dst + 4096 + p * 2048);
  }

  int cbuf = 0, nbuf = 2;
  for (int i = 0; i < niter; ++i) {
    if (i + 2 < niter) {
      const int k2 = (i + 2) << 6;
      short* dst = SMEM + nbuf * 12288 + t8;
#pragma unroll
      for (int p = 0; p < 2; ++p) glds16(Ag + k2 + p * pstr, dst + p * 2048);
#pragma unroll
      for (int p = 0; p < 4; ++p) glds16(Bg + k2 + p * pstr, dst + 4096 + p * 2048);
      nbuf = (nbuf == 2) ? 0 : nbuf + 1;
      WAITV(12);
    } else if (i + 1 < niter) {
      WAITV(6);
    } else {
      WAITV(0);
    }
    SBAR();

    const short* As = SMEM + cbuf * 12288;
    const short* Bs = As + 4096;
    cbuf = (cbuf == 2) ? 0 : cbuf + 1;
#pragma unroll
    for (int kk = 0; kk < 2; ++kk) {
      s8v af[2], bf[4];
#pragma unroll
      for (int ii = 0; ii < 2; ++ii)
        af[ii] = *(const s8v*)&As[(wm + ii * 16 + l16) * 64 + (((kk * 4 + quad) ^ swq) * 8)];
#pragma unroll
      for (int j = 0; j < 4; ++j)
        bf[j] = *(const s8v*)&Bs[(wn + j * 16 + l16) * 64 + (((kk * 4 + quad) ^ swq) * 8)];
#pragma unroll
      for (int ii = 0; ii < 2; ++ii)
#pragma unroll
        for (int j = 0; j < 4; ++j)
          acc[ii][j] = __builtin_amdgcn_mfma_f32_16x16x32_bf16(af[ii], bf[j], acc[ii][j], 0, 0, 0);
    }
    SBAR();
  }

  float* Cf = out + (size_t)bz * S_LEN * D_DIM;
#pragma unroll
  for (int i = 0; i < 2; ++i) {
#pragma unroll
    for (int j = 0; j < 4; ++j) {
      const int gn = n0 + wn + j * 16 + l16;
      const float tvn = Tv[(bz << 9) + gn];
#pragma unroll
      for (int r = 0; r < 4; ++r) {
        const int gm = m0 + wm + i * 16 + quad * 4 + r;
        Cf[(size_t)gm * D_DIM + gn] = acc[i][j][r] + tvn;
      }
    }
  }
}

// fp32 -> bf16, 8 elems/thread, three source arrays -> contiguous dst slabs
__global__ __launch_bounds__(256) void cvt3(
    const float* __restrict__ s0, const float* __restrict__ s1,
    const float* __restrict__ s2, short* __restrict__ dst, int n)
{
  const float* s = (blockIdx.y == 0) ? s0 : (blockIdx.y == 1) ? s1 : s2;
  short* d = dst + (size_t)blockIdx.y * n;
  const int i = (blockIdx.x * 256 + threadIdx.x) * 8;
  if (i >= n) return;
  const float4 f0 = *(const float4*)(s + i);
  const float4 f1 = *(const float4*)(s + i + 4);
  s8v o;
  o[0] = f2bf_s(f0.x); o[1] = f2bf_s(f0.y); o[2] = f2bf_s(f0.z); o[3] = f2bf_s(f0.w);
  o[4] = f2bf_s(f1.x); o[5] = f2bf_s(f1.y); o[6] = f2bf_s(f1.z); o[7] = f2bf_s(f1.w);
  *(s8v*)(d + i) = o;
}

// block per (b,d): vpT[b][d][k] /= (2048+ZF[b][k]); Tv[b,d] = sum_k (fp32)
__global__ __launch_bounds__(256) void scale_vpt_T(
    short* __restrict__ vpT, const float* __restrict__ ZF, float* __restrict__ Tv)
{
  __shared__ float red[4];
  const int b = blockIdx.y, d = blockIdx.x, tid = threadIdx.x;
  const size_t rowbase = ((size_t)(b * D_DIM + d)) * S_LEN;
  const float* zf = ZF + (b << 11);
  const int k0 = tid * 8;

  s8v v = *(s8v*)&vpT[rowbase + k0];
  float s = 0.0f;
#pragma unroll
  for (int i = 0; i < 8; ++i) {
    const float w = bf2f_s(v[i]) / (2048.0f + zf[k0 + i]);
    s += w;
    v[i] = f2bf_s(w);
  }
  *(s8v*)&vpT[rowbase + k0] = v;

#pragma unroll
  for (int off = 32; off >= 1; off >>= 1) s += __shfl_xor(s, off, 64);
  if ((tid & 63) == 0) red[tid >> 6] = s;
  __syncthreads();
  if (tid == 0) Tv[(b << 9) + d] = red[0] + red[1] + red[2] + red[3];
}

extern "C" void kernel_launch(void* const* d_in, const int* in_sizes, int n_in,
                              void* d_out, int out_size, void* d_ws, size_t ws_size,
                              hipStream_t stream) {
  const float* q   = (const float*)d_in[0];
  const float* k   = (const float*)d_in[1];
  const float* v   = (const float*)d_in[2];
  const float* WQw = (const float*)d_in[3];
  const float* WQb = (const float*)d_in[4];
  const float* WKw = (const float*)d_in[5];
  const float* WKb = (const float*)d_in[6];
  const float* WVw = (const float*)d_in[7];
  const float* WVb = (const float*)d_in[8];

  char* ws = (char*)d_ws;
  // F occupies [0,32M); bf16 input/weight copies alias its head (dead before F written)
  short* F   = (short*)(ws);                 // 32 MB  [4][2048][2048] (lower tiles only)
  short* qb  = (short*)(ws);                 //  8 MB  (qb,kb,vb contiguous)
  short* Wqb = (short*)(ws + 25165824);      // 3x 512 KB contiguous
  short* qp  = (short*)(ws + 33554432);      //  8 MB  [4][2048][512]
  short* kp  = (short*)(ws + 41943040);      //  8 MB
  short* vpT = (short*)(ws + 50331648);      //  8 MB  [4][512][2048]
  float* ZF  = (float*)(ws + 58720256);      // 32 KB  [4][2048]
  float* Tv  = (float*)(ws + 58753024);      //  8 KB  [4][512]
  short* kb  = qb + 4194304;
  short* vb  = qb + 8388608;
  short* Wkb = Wqb + 262144;
  short* Wvb = Wqb + 524288;

  const dim3 blk(256);

  hipMemsetAsync(ZF, 0, 4 * S_LEN * sizeof(float), stream);

  cvt3<<<dim3(2048, 3), blk, 0, stream>>>(q, k, v, qb, 4194304);
  cvt3<<<dim3(128, 3), blk, 0, stream>>>(WQw, WKw, WVw, Wqb, 262144);

  // projections: M=8192, N=512, K=512 — one launch, 768 blocks
  proj3<<<dim3(4, 64, 3), blk, 0, stream>>>(
      qb, kb, vb, Wqb, Wkb, Wvb, qp, kp, vpT, WQb, WKb, WVb);

  // F = expm1(scale*qp@kp^T) lower-tri tiles + fused ZF colsum: 136 tiles/batch
  gemm_scoresF<<<dim3(136, 1, 4), blk, 0, stream>>>(qp, kp, F, ZF);

  // vpT' = vpT/(2048+ZF); Tv = rowsum(vpT')
  scale_vpt_T<<<dim3(512, 4), blk, 0, stream>>>(vpT, ZF, Tv);

  // out = F @ vpT'^T + Tv: 64x128 tiles, K truncated at m0+64
  gemm_outF<<<dim3(4, 32, 4), blk, 0, stream>>>(F, vpT, Tv, (float*)d_out);
}